// Round 6
// baseline (15480.911 us; speedup 1.0000x reference)
//
#include <hip/hip_runtime.h>
#include <math.h>

// EncoderRNN persistent kernel, round 11 = round 6 (best PASSING, 11.0ms) +
// two serial-CP-round-trip cuts. r10's lesson applied: poll CONTENTION is the
// scarce resource -> keep polling on ONE broadcast line (like r6's gen).
//  (1) Barrier: single-counter arrival. After the vmcnt-draining __syncthreads,
//      tid0 does agent-scope atomicAdd(ctr,1); one wave polls ctr >= 256*(j+1)
//      (one line, all lanes same addr = 1 req/iter/block, same pattern as
//      r6's proven gen poll). Removes the flag->block0->gen 2-hop chain
//      (~1.6-2.2us) for ~0.8us. Full-barrier semantics unchanged -> ordered
//      out store/load-add stays valid. Monotonic ctr, no reset needed.
//  (2) Out-partner prefetch: the load-add partner value was written >=1
//      epoch earlier (fwd adds torig>=512 at step torig+1, bwd wrote it at
//      step SEQ-torig <= j-1; symmetric for bwd) -> prefetch at step TOP
//      (overlaps staging+MFMA) instead of a dependent CP load in the cell
//      phase of the straggler layer-2 blocks.
// Everything else r6 verbatim (emb convert-on-fly, packed-u32 h exchange,
// K-split MFMA, LDS layout, cell math). absmax must stay 0.0001220703.
// Predicted: pass, dur 11.0 -> ~9.7-10.4ms, bank-conflict ~1.0e8 unchanged.

#define SEQ 1024
#define NB 32
#define NH 512
#define BH (NB*NH)
#define KP 1032   // LDS row stride in shorts = 2064 B (odd 16B slots)

typedef __attribute__((ext_vector_type(8))) short short8;
typedef __attribute__((ext_vector_type(4))) float f32x4;
typedef unsigned long long u64;

struct P {
  const int*   word;
  const float* emb;
  const float* Wih[4];   // dl = dir*2+layer: 0=fwd1,1=fwd2,2=bwd1,3=bwd2
  const float* Whh[4];
  const float* bih[4];
  const float* bhh[4];
  unsigned* ctr;         // single 64B line: monotonic arrival counter
  unsigned* hpk;         // [4 dl][2 par][NB][NH] u32 = (bf16hi | bf16lo<<16)
  float* out;
};

__device__ __forceinline__ unsigned short f2bf(float x) {
  unsigned u = __float_as_uint(x);
  return (unsigned short)((u + 0x7fffu + ((u >> 16) & 1u)) >> 16);  // RNE
}
__device__ __forceinline__ float bf2f(unsigned short b) {
  return __uint_as_float(((unsigned)b) << 16);
}
__device__ __forceinline__ float sigf(float x) { return 1.0f / (1.0f + expf(-x)); }

__device__ __forceinline__ unsigned ald(const unsigned* p_) {
  return __hip_atomic_load((unsigned*)p_, __ATOMIC_RELAXED, __HIP_MEMORY_SCOPE_AGENT);
}
__device__ __forceinline__ u64 ald64(const u64* p_) {
  return __hip_atomic_load((u64*)p_, __ATOMIC_RELAXED, __HIP_MEMORY_SCOPE_AGENT);
}
__device__ __forceinline__ void ast(unsigned* p_, unsigned v) {
  __hip_atomic_store(p_, v, __ATOMIC_RELAXED, __HIP_MEMORY_SCOPE_AGENT);
}
__device__ __forceinline__ float aldf(const float* p_) {
  return __hip_atomic_load((float*)p_, __ATOMIC_RELAXED, __HIP_MEMORY_SCOPE_AGENT);
}
__device__ __forceinline__ void astf(float* p_, float v) {
  __hip_atomic_store(p_, v, __ATOMIC_RELAXED, __HIP_MEMORY_SCOPE_AGENT);
}

// stage 64 packed-u32 h elements (agent-coherent) -> 64 hi + 64 lo shorts in
// LDS (round-6 proven path).
__device__ __forceinline__ void stage_h_slice(const unsigned* src,
                                              unsigned short* dHi,
                                              unsigned short* dLo) {
  u64 A[32];
#pragma unroll
  for (int q = 0; q < 32; ++q) A[q] = ald64((const u64*)src + q);
#pragma unroll
  for (int q = 0; q < 8; ++q) {
    unsigned hw[4], lw[4];
#pragma unroll
    for (int m = 0; m < 4; ++m) {
      const unsigned w0 = (unsigned)A[4*q + m];
      const unsigned w1 = (unsigned)(A[4*q + m] >> 32);
      hw[m] = (w0 & 0xffffu) | (w1 << 16);
      lw[m] = (w0 >> 16)     | (w1 & 0xffff0000u);
    }
    uint4 hv, lv;
    hv.x = hw[0]; hv.y = hw[1]; hv.z = hw[2]; hv.w = hw[3];
    lv.x = lw[0]; lv.y = lw[1]; lv.z = lw[2]; lv.w = lw[3];
    *(uint4*)(dHi + q*8) = hv;
    *(uint4*)(dLo + q*8) = lv;
  }
}

__global__ __launch_bounds__(256, 1) void enc_persist(P p) {
  extern __shared__ unsigned short smem[];
  unsigned short* xhHi = smem;              // [16][KP]
  unsigned short* xhLo = smem + 16 * KP;    // [16][KP]
  float* gl2 = (float*)(smem + 32 * KP);    // [4 wv][4 gate][16 batch][20] fp32

  const int tid  = threadIdx.x;
  const int bid  = blockIdx.x;
  const int dl   = bid >> 6;
  const int dir  = dl >> 1, layer = dl & 1;
  const int r6   = bid & 63;
  const int u0   = (r6 >> 1) * 16;   // 32 unit-groups of 16
  const int b0   = (r6 & 1) * 16;    // 2 batch-halves of 16
  const int lane = tid & 63, wv = tid >> 6;   // wave wv owns kc in [8wv, 8wv+8)

  // ---- prologue: W fragments (bf16 hi/lo) for all 4 gates, this wave's K ----
  short8 aHi[32], aLo[32];   // index gg*8+kk
  {
    const int kg = (lane >> 4) * 8;
#pragma unroll
    for (int gg = 0; gg < 4; ++gg) {
      const int gr = gg * 512 + u0 + (lane & 15);   // global gate row
      const float* Wi = p.Wih[dl] + (size_t)gr * NH;
      const float* Wh = p.Whh[dl] + (size_t)gr * NH;
#pragma unroll
      for (int kk = 0; kk < 8; ++kk) {
        const int k0 = (wv * 8 + kk) * 32 + kg;
        const float* s = (k0 < 512) ? (Wi + k0) : (Wh + (k0 - 512));
        float4 v0 = *(const float4*)s;
        float4 v1 = *(const float4*)(s + 4);
        float xs[8] = {v0.x, v0.y, v0.z, v0.w, v1.x, v1.y, v1.z, v1.w};
        short8 h8, l8;
#pragma unroll
        for (int q = 0; q < 8; ++q) {
          unsigned short hb = f2bf(xs[q]);
          h8[q] = (short)hb;
          l8[q] = (short)f2bf(xs[q] - bf2f(hb));
        }
        aHi[gg * 8 + kk] = h8; aLo[gg * 8 + kk] = l8;
      }
    }
  }

  // cell thread mapping: cb = batch-local (tid>>4), cu = unit (tid&15)
  const int cu = tid & 15, cb = tid >> 4;
  const int uG = u0 + cu;
  const float bi  = p.bih[dl][uG]        + p.bhh[dl][uG];
  const float bf_ = p.bih[dl][512 + uG]  + p.bhh[dl][512 + uG];
  const float bg  = p.bih[dl][1024 + uG] + p.bhh[dl][1024 + uG];
  const float bo  = p.bih[dl][1536 + uG] + p.bhh[dl][1536 + uG];

  float c_reg = 0.f, h_reg = 0.f;

  // staging thread mapping: rb = row (tid&15), sr = k-slice (tid>>4)
  const int sr = tid >> 4;
  const int rb = tid & 15;
  const int ks = sr * 64;      // this thread's 64-short slice of the row

  int tk, tk_st;
  {
    const int to0 = dir ? (SEQ - 1) : 0;
    tk    = p.word[(size_t)to0 * NB + b0 + cb];   // cell mask token
    tk_st = p.word[(size_t)to0 * NB + b0 + rb];   // staging-row token
  }

  for (int j = 0; j <= SEQ; ++j) {
    const int act = layer ? (j >= 1) : (j < SEQ);
    const int t = layer ? (j - 1) : j;
    const int torig = dir ? (SEQ - 1 - t) : t;
    const int par = j & 1;

    if (act) {
      // ---- stage one row-slice of [x(512);h(512)] bf16 hi/lo into LDS ----
      if (sr < 8) {   // x-part, k in [0,512)  (waves 0-1, uniform)
        if (layer == 0) {  // embedding fp32, convert on the fly (round-6 path)
          const float* e = p.emb + (size_t)tk_st * NH + ks;
#pragma unroll
          for (int h2 = 0; h2 < 2; ++h2) {
            float4 v[8];
#pragma unroll
            for (int q = 0; q < 8; ++q) v[q] = *(const float4*)(e + h2 * 32 + q * 4);
#pragma unroll
            for (int q = 0; q < 4; ++q) {
              float xs[8] = {v[2*q].x, v[2*q].y, v[2*q].z, v[2*q].w,
                             v[2*q+1].x, v[2*q+1].y, v[2*q+1].z, v[2*q+1].w};
              unsigned hw[4], lw[4];
#pragma unroll
              for (int m = 0; m < 4; ++m) {
                unsigned short ha = f2bf(xs[2*m]);
                unsigned short hc = f2bf(xs[2*m+1]);
                unsigned short la = f2bf(xs[2*m]   - bf2f(ha));
                unsigned short lc = f2bf(xs[2*m+1] - bf2f(hc));
                hw[m] = (unsigned)ha | ((unsigned)hc << 16);
                lw[m] = (unsigned)la | ((unsigned)lc << 16);
              }
              uint4 hv, lv;
              hv.x=hw[0]; hv.y=hw[1]; hv.z=hw[2]; hv.w=hw[3];
              lv.x=lw[0]; lv.y=lw[1]; lv.z=lw[2]; lv.w=lw[3];
              *(uint4*)(xhHi + rb * KP + ks + h2 * 32 + q * 8) = hv;
              *(uint4*)(xhLo + rb * KP + ks + h2 * 32 + q * 8) = lv;
            }
          }
        } else {      // layer2 x = layer1 h (packed u32, agent-coherent)
          const size_t hb = (size_t)((dl - 1) * 2 + par) * BH + (size_t)(b0 + rb) * NH + ks;
          stage_h_slice(p.hpk + hb, xhHi + rb * KP + ks, xhLo + rb * KP + ks);
        }
      } else {        // recurrent half, k in [512,1024)  (waves 2-3, uniform)
        const size_t hb = (size_t)(dl * 2 + par) * BH + (size_t)(b0 + rb) * NH + (ks - 512);
        stage_h_slice(p.hpk + hb, xhHi + rb * KP + ks, xhLo + rb * KP + ks);
      }
    }

    // prefetch next step's tokens (latency hides under MFMA+cell+barrier)
    int tk_nx = tk, tk_st_nx = tk_st;
    if (j < SEQ) {
      int t_nx = layer ? j : (j + 1);
      if (t_nx > SEQ - 1) t_nx = SEQ - 1;
      const int to_nx = dir ? (SEQ - 1 - t_nx) : t_nx;
      tk_nx    = p.word[(size_t)to_nx * NB + b0 + cb];
      tk_st_nx = p.word[(size_t)to_nx * NB + b0 + rb];
    }

    // ---- out-partner prefetch (layer2 add-case only). Partner value was
    // written >=1 barrier epoch ago (margin proof in header) -> safe to load
    // at step top; overlaps staging/MFMA instead of stalling the cell.
    float out_pf = 0.f;
    size_t oi = 0;
    int do_add = 0;
    if (act && layer == 1) {
      oi = (size_t)torig * BH + (size_t)(b0 + cb) * NH + uG;
      do_add = dir ? (torig < 512) : (torig > 511);
      if (do_add) out_pf = aldf(p.out + oi);
    }

    __syncthreads();

    if (act) {
      // ---- K-split MFMA: wave wv sums kc in [8wv,8wv+8) for all 4 gates ----
      f32x4 aA[4], aBC[4];
#pragma unroll
      for (int gg = 0; gg < 4; ++gg) {
        aA[gg]  = (f32x4){0.f, 0.f, 0.f, 0.f};
        aBC[gg] = (f32x4){0.f, 0.f, 0.f, 0.f};
      }
      const unsigned short* bp = xhHi + (lane & 15) * KP + (lane >> 4) * 8;
      const unsigned short* bq = xhLo + (lane & 15) * KP + (lane >> 4) * 8;
#pragma unroll
      for (int kk = 0; kk < 8; ++kk) {
        const int kc = wv * 8 + kk;
        short8 bH = *(const short8*)(bp + kc * 32);
        short8 bL = *(const short8*)(bq + kc * 32);
#pragma unroll
        for (int gg = 0; gg < 4; ++gg) {
          aA[gg]  = __builtin_amdgcn_mfma_f32_16x16x32_bf16(aHi[gg*8+kk], bH, aA[gg],  0, 0, 0);
          aBC[gg] = __builtin_amdgcn_mfma_f32_16x16x32_bf16(aLo[gg*8+kk], bH, aBC[gg], 0, 0, 0);
          aBC[gg] = __builtin_amdgcn_mfma_f32_16x16x32_bf16(aHi[gg*8+kk], bL, aBC[gg], 0, 0, 0);
        }
      }
      // C/D (m89): col = lane&15 = batch, row = (lane>>4)*4 + reg = unit
#pragma unroll
      for (int gg = 0; gg < 4; ++gg) {
        f32x4 acc = aA[gg] + aBC[gg];
        *(f32x4*)&gl2[((wv * 4 + gg) * 16 + (lane & 15)) * 20 + (lane >> 4) * 4] = acc;
      }
    }
    __syncthreads();

    if (act) {
      // ---- fused cell: tree-sum the 4 waves' K-partials ----
#define GL2(w_,g_) gl2[(((w_) * 4 + (g_)) * 16 + cb) * 20 + cu]
      const float vi = ((GL2(0,0)+GL2(1,0)) + (GL2(2,0)+GL2(3,0))) + bi;
      const float vf = ((GL2(0,1)+GL2(1,1)) + (GL2(2,1)+GL2(3,1))) + bf_;
      const float vg = ((GL2(0,2)+GL2(1,2)) + (GL2(2,2)+GL2(3,2))) + bg;
      const float vo = ((GL2(0,3)+GL2(1,3)) + (GL2(2,3)+GL2(3,3))) + bo;
#undef GL2
      float cn = sigf(vf) * c_reg + sigf(vi) * tanhf(vg);
      float hn = sigf(vo) * tanhf(cn);
      if (tk == 1) { cn = c_reg; hn = h_reg; }
      c_reg = cn; h_reg = hn;
      const unsigned short hh = f2bf(hn);
      const unsigned short hl = f2bf(hn - bf2f(hh));
      const size_t hix = (size_t)(dl * 2 + (par ^ 1)) * BH + (size_t)(b0 + cb) * NH + uG;
      ast(p.hpk + hix, (unsigned)hh | ((unsigned)hl << 16));
      if (layer == 1) {
        // ordered by the full device barrier per step; partner value prefetched
        const float v = dir ? (0.5f * hn) : hn;
        astf(p.out + oi, do_add ? (out_pf + v) : v);
      }
    }

    tk = tk_nx; tk_st = tk_st_nx;

    // ---- single-counter full barrier (1 arrival RMW + 1-line broadcast poll) ----
    __syncthreads();   // drains vmcnt -> all sc1 stores acked at coherence point
    if (tid == 0)
      (void)__hip_atomic_fetch_add(p.ctr, 1u, __ATOMIC_RELAXED,
                                   __HIP_MEMORY_SCOPE_AGENT);
    if (tid < 64) {
      const unsigned tgt = (unsigned)(j + 1) * 256u;
      while (ald(p.ctr) < tgt) __builtin_amdgcn_s_sleep(1);
    }
    __syncthreads();
  }

  // ---- epilogue: backward final carries bh1,bc1,bh2,bc2 ----
  if (dl == 2) {
    p.out[(size_t)SEQ * BH + 0 * (size_t)BH + (size_t)(b0 + cb) * NH + uG] = h_reg;
    p.out[(size_t)SEQ * BH + 1 * (size_t)BH + (size_t)(b0 + cb) * NH + uG] = c_reg;
  } else if (dl == 3) {
    p.out[(size_t)SEQ * BH + 2 * (size_t)BH + (size_t)(b0 + cb) * NH + uG] = h_reg;
    p.out[(size_t)SEQ * BH + 3 * (size_t)BH + (size_t)(b0 + cb) * NH + uG] = c_reg;
  }
}

extern "C" void kernel_launch(void* const* d_in, const int* in_sizes, int n_in,
                              void* d_out, int out_size, void* d_ws, size_t ws_size,
                              hipStream_t stream) {
  P p;
  p.word = (const int*)d_in[0];
  p.emb  = (const float*)d_in[1];
  for (int i = 0; i < 4; ++i) {
    p.Wih[i] = (const float*)d_in[2 + i * 4 + 0];
    p.Whh[i] = (const float*)d_in[2 + i * 4 + 1];
    p.bih[i] = (const float*)d_in[2 + i * 4 + 2];
    p.bhh[i] = (const float*)d_in[2 + i * 4 + 3];
  }
  unsigned char* ws = (unsigned char*)d_ws;
  p.ctr = (unsigned*)ws;                         // one 64B line
  p.hpk = (unsigned*)(ws + 16384);               // 512 KB packed h
  p.out = (float*)d_out;

  hipMemsetAsync(d_ws, 0, 16384 + (size_t)8 * BH * 4, stream);

  // used: 32*KP*2 + 4*4*16*20*4 = 86528 B; request 88 KB to keep 1 block/CU
  const int smem = 90112;
  hipFuncSetAttribute(reinterpret_cast<const void*>(enc_persist),
                      hipFuncAttributeMaxDynamicSharedMemorySize, smem);
  hipLaunchKernelGGL(enc_persist, dim3(256), dim3(256), smem, stream, p);
}

// Round 7
// 10839.616 us; speedup vs baseline: 1.4282x; 1.4282x over previous
//
#include <hip/hip_runtime.h>
#include <math.h>

// EncoderRNN persistent kernel, round 12 = round 6 (best PASSING, 11.0ms)
// + two LATENCY-OVERLAP changes only. Barrier protocol, ordering, LDS layout,
// MFMA, cell math: r6 VERBATIM. Lessons applied: r10/r11 mapped the barrier
// design space -> r6's {distributed flag stores + single gather + stable
// single-line broadcast poll} is the local optimum; stop touching it.
//  (ii) out-partner prefetch (r11-proven-correct piece): layer2's load-add
//       partner was written >=1 barrier epoch earlier -> load at step TOP
//       (overlaps h-staging latency) instead of a dependent ~0.9us CP round
//       trip inside the cell phase of the straggler layer-2 blocks.
//  (iii) emb prefetch during barrier wait: layer0 x-rows for step j+1 are
//       known (token prefetched) and emb is read-only -> issue the 16 float4
//       loads right AFTER the flag store, in flight through the gen-wait,
//       consume (convert+LDS-write) after release. Hides HBM-miss jitter
//       (~0.9us) that otherwise stalls all 256 blocks via the barrier.
// Predicted: pass, absmax 0.0001220703 identical, dur 11.0 -> ~9.9-10.5ms,
// VGPR ~300-340 (watch for 512/scratch = failure mode), bank-conflict ~1.0e8.

#define SEQ 1024
#define NB 32
#define NH 512
#define BH (NB*NH)
#define KP 1032   // LDS row stride in shorts = 2064 B (odd 16B slots)

typedef __attribute__((ext_vector_type(8))) short short8;
typedef __attribute__((ext_vector_type(4))) float f32x4;
typedef unsigned long long u64;

struct P {
  const int*   word;
  const float* emb;
  const float* Wih[4];   // dl = dir*2+layer: 0=fwd1,1=fwd2,2=bwd1,3=bwd2
  const float* Whh[4];
  const float* bih[4];
  const float* bhh[4];
  unsigned* flags;       // 256 slots, stride 16 u32 (one 64B line each)
  unsigned* gen;         // single 64B line
  unsigned* hpk;         // [4 dl][2 par][NB][NH] u32 = (bf16hi | bf16lo<<16)
  float* out;
};

__device__ __forceinline__ unsigned short f2bf(float x) {
  unsigned u = __float_as_uint(x);
  return (unsigned short)((u + 0x7fffu + ((u >> 16) & 1u)) >> 16);  // RNE
}
__device__ __forceinline__ float bf2f(unsigned short b) {
  return __uint_as_float(((unsigned)b) << 16);
}
__device__ __forceinline__ float sigf(float x) { return 1.0f / (1.0f + expf(-x)); }

__device__ __forceinline__ unsigned ald(const unsigned* p_) {
  return __hip_atomic_load((unsigned*)p_, __ATOMIC_RELAXED, __HIP_MEMORY_SCOPE_AGENT);
}
__device__ __forceinline__ u64 ald64(const u64* p_) {
  return __hip_atomic_load((u64*)p_, __ATOMIC_RELAXED, __HIP_MEMORY_SCOPE_AGENT);
}
__device__ __forceinline__ void ast(unsigned* p_, unsigned v) {
  __hip_atomic_store(p_, v, __ATOMIC_RELAXED, __HIP_MEMORY_SCOPE_AGENT);
}
__device__ __forceinline__ float aldf(const float* p_) {
  return __hip_atomic_load((float*)p_, __ATOMIC_RELAXED, __HIP_MEMORY_SCOPE_AGENT);
}
__device__ __forceinline__ void astf(float* p_, float v) {
  __hip_atomic_store(p_, v, __ATOMIC_RELAXED, __HIP_MEMORY_SCOPE_AGENT);
}

// stage 64 packed-u32 h elements (agent-coherent) -> 64 hi + 64 lo shorts in
// LDS (round-6 proven path).
__device__ __forceinline__ void stage_h_slice(const unsigned* src,
                                              unsigned short* dHi,
                                              unsigned short* dLo) {
  u64 A[32];
#pragma unroll
  for (int q = 0; q < 32; ++q) A[q] = ald64((const u64*)src + q);
#pragma unroll
  for (int q = 0; q < 8; ++q) {
    unsigned hw[4], lw[4];
#pragma unroll
    for (int m = 0; m < 4; ++m) {
      const unsigned w0 = (unsigned)A[4*q + m];
      const unsigned w1 = (unsigned)(A[4*q + m] >> 32);
      hw[m] = (w0 & 0xffffu) | (w1 << 16);
      lw[m] = (w0 >> 16)     | (w1 & 0xffff0000u);
    }
    uint4 hv, lv;
    hv.x = hw[0]; hv.y = hw[1]; hv.z = hw[2]; hv.w = hw[3];
    lv.x = lw[0]; lv.y = lw[1]; lv.z = lw[2]; lv.w = lw[3];
    *(uint4*)(dHi + q*8) = hv;
    *(uint4*)(dLo + q*8) = lv;
  }
}

__global__ __launch_bounds__(256, 1) void enc_persist(P p) {
  extern __shared__ unsigned short smem[];
  unsigned short* xhHi = smem;              // [16][KP]
  unsigned short* xhLo = smem + 16 * KP;    // [16][KP]
  float* gl2 = (float*)(smem + 32 * KP);    // [4 wv][4 gate][16 batch][20] fp32

  const int tid  = threadIdx.x;
  const int bid  = blockIdx.x;
  const int dl   = bid >> 6;
  const int dir  = dl >> 1, layer = dl & 1;
  const int r6   = bid & 63;
  const int u0   = (r6 >> 1) * 16;   // 32 unit-groups of 16
  const int b0   = (r6 & 1) * 16;    // 2 batch-halves of 16
  const int lane = tid & 63, wv = tid >> 6;   // wave wv owns kc in [8wv, 8wv+8)

  // ---- prologue: W fragments (bf16 hi/lo) for all 4 gates, this wave's K ----
  short8 aHi[32], aLo[32];   // index gg*8+kk
  {
    const int kg = (lane >> 4) * 8;
#pragma unroll
    for (int gg = 0; gg < 4; ++gg) {
      const int gr = gg * 512 + u0 + (lane & 15);   // global gate row
      const float* Wi = p.Wih[dl] + (size_t)gr * NH;
      const float* Wh = p.Whh[dl] + (size_t)gr * NH;
#pragma unroll
      for (int kk = 0; kk < 8; ++kk) {
        const int k0 = (wv * 8 + kk) * 32 + kg;
        const float* s = (k0 < 512) ? (Wi + k0) : (Wh + (k0 - 512));
        float4 v0 = *(const float4*)s;
        float4 v1 = *(const float4*)(s + 4);
        float xs[8] = {v0.x, v0.y, v0.z, v0.w, v1.x, v1.y, v1.z, v1.w};
        short8 h8, l8;
#pragma unroll
        for (int q = 0; q < 8; ++q) {
          unsigned short hb = f2bf(xs[q]);
          h8[q] = (short)hb;
          l8[q] = (short)f2bf(xs[q] - bf2f(hb));
        }
        aHi[gg * 8 + kk] = h8; aLo[gg * 8 + kk] = l8;
      }
    }
  }

  // cell thread mapping: cb = batch-local (tid>>4), cu = unit (tid&15)
  const int cu = tid & 15, cb = tid >> 4;
  const int uG = u0 + cu;
  const float bi  = p.bih[dl][uG]        + p.bhh[dl][uG];
  const float bf_ = p.bih[dl][512 + uG]  + p.bhh[dl][512 + uG];
  const float bg  = p.bih[dl][1024 + uG] + p.bhh[dl][1024 + uG];
  const float bo  = p.bih[dl][1536 + uG] + p.bhh[dl][1536 + uG];

  float c_reg = 0.f, h_reg = 0.f;

  // staging thread mapping: rb = row (tid&15), sr = k-slice (tid>>4)
  const int sr = tid >> 4;
  const int rb = tid & 15;
  const int ks = sr * 64;      // this thread's 64-short slice of the row

  int tk, tk_st;
  {
    const int to0 = dir ? (SEQ - 1) : 0;
    tk    = p.word[(size_t)to0 * NB + b0 + cb];   // cell mask token
    tk_st = p.word[(size_t)to0 * NB + b0 + rb];   // staging-row token
  }

  // (iii) emb prefetch registers: 64 floats = this thread's x-slice for the
  // NEXT active step. Only meaningful on layer-0 blocks, waves 0-1.
  const bool do_epf = (layer == 0) && (sr < 8);
  float4 epf[16];
  if (do_epf) {   // prologue prefetch for j=0
    const float* e = p.emb + (size_t)tk_st * NH + ks;
#pragma unroll
    for (int q = 0; q < 16; ++q) epf[q] = *(const float4*)(e + q * 4);
  }

  for (int j = 0; j <= SEQ; ++j) {
    const int act = layer ? (j >= 1) : (j < SEQ);
    const int t = layer ? (j - 1) : j;
    const int torig = dir ? (SEQ - 1 - t) : t;
    const int par = j & 1;

    if (act) {
      // ---- stage one row-slice of [x(512);h(512)] bf16 hi/lo into LDS ----
      if (sr < 8) {   // x-part, k in [0,512)  (waves 0-1, uniform)
        if (layer == 0) {  // convert prefetched emb registers (same RNE math)
#pragma unroll
          for (int h2 = 0; h2 < 2; ++h2) {
#pragma unroll
            for (int q = 0; q < 4; ++q) {
              const float4 va = epf[h2 * 8 + 2 * q];
              const float4 vb = epf[h2 * 8 + 2 * q + 1];
              float xs[8] = {va.x, va.y, va.z, va.w, vb.x, vb.y, vb.z, vb.w};
              unsigned hw[4], lw[4];
#pragma unroll
              for (int m = 0; m < 4; ++m) {
                unsigned short ha = f2bf(xs[2*m]);
                unsigned short hc = f2bf(xs[2*m+1]);
                unsigned short la = f2bf(xs[2*m]   - bf2f(ha));
                unsigned short lc = f2bf(xs[2*m+1] - bf2f(hc));
                hw[m] = (unsigned)ha | ((unsigned)hc << 16);
                lw[m] = (unsigned)la | ((unsigned)lc << 16);
              }
              uint4 hv, lv;
              hv.x=hw[0]; hv.y=hw[1]; hv.z=hw[2]; hv.w=hw[3];
              lv.x=lw[0]; lv.y=lw[1]; lv.z=lw[2]; lv.w=lw[3];
              *(uint4*)(xhHi + rb * KP + ks + h2 * 32 + q * 8) = hv;
              *(uint4*)(xhLo + rb * KP + ks + h2 * 32 + q * 8) = lv;
            }
          }
        } else {      // layer2 x = layer1 h (packed u32, agent-coherent)
          const size_t hb = (size_t)((dl - 1) * 2 + par) * BH + (size_t)(b0 + rb) * NH + ks;
          stage_h_slice(p.hpk + hb, xhHi + rb * KP + ks, xhLo + rb * KP + ks);
        }
      } else {        // recurrent half, k in [512,1024)  (waves 2-3, uniform)
        const size_t hb = (size_t)(dl * 2 + par) * BH + (size_t)(b0 + rb) * NH + (ks - 512);
        stage_h_slice(p.hpk + hb, xhHi + rb * KP + ks, xhLo + rb * KP + ks);
      }
    }

    // prefetch next step's tokens (latency hides under MFMA+cell+barrier)
    int tk_nx = tk, tk_st_nx = tk_st;
    if (j < SEQ) {
      int t_nx = layer ? j : (j + 1);
      if (t_nx > SEQ - 1) t_nx = SEQ - 1;
      const int to_nx = dir ? (SEQ - 1 - t_nx) : t_nx;
      tk_nx    = p.word[(size_t)to_nx * NB + b0 + cb];
      tk_st_nx = p.word[(size_t)to_nx * NB + b0 + rb];
    }

    // (ii) out-partner prefetch (layer2 add-case). Partner value was written
    // >=1 barrier epoch ago -> safe to load at step top; overlaps staging.
    float out_pf = 0.f;
    size_t oi = 0;
    int do_add = 0;
    if (act && layer == 1) {
      oi = (size_t)torig * BH + (size_t)(b0 + cb) * NH + uG;
      do_add = dir ? (torig < 512) : (torig > 511);
      if (do_add) out_pf = aldf(p.out + oi);
    }

    __syncthreads();

    if (act) {
      // ---- K-split MFMA: wave wv sums kc in [8wv,8wv+8) for all 4 gates ----
      f32x4 aA[4], aBC[4];
#pragma unroll
      for (int gg = 0; gg < 4; ++gg) {
        aA[gg]  = (f32x4){0.f, 0.f, 0.f, 0.f};
        aBC[gg] = (f32x4){0.f, 0.f, 0.f, 0.f};
      }
      const unsigned short* bp = xhHi + (lane & 15) * KP + (lane >> 4) * 8;
      const unsigned short* bq = xhLo + (lane & 15) * KP + (lane >> 4) * 8;
#pragma unroll
      for (int kk = 0; kk < 8; ++kk) {
        const int kc = wv * 8 + kk;
        short8 bH = *(const short8*)(bp + kc * 32);
        short8 bL = *(const short8*)(bq + kc * 32);
#pragma unroll
        for (int gg = 0; gg < 4; ++gg) {
          aA[gg]  = __builtin_amdgcn_mfma_f32_16x16x32_bf16(aHi[gg*8+kk], bH, aA[gg],  0, 0, 0);
          aBC[gg] = __builtin_amdgcn_mfma_f32_16x16x32_bf16(aLo[gg*8+kk], bH, aBC[gg], 0, 0, 0);
          aBC[gg] = __builtin_amdgcn_mfma_f32_16x16x32_bf16(aHi[gg*8+kk], bL, aBC[gg], 0, 0, 0);
        }
      }
      // C/D (m89): col = lane&15 = batch, row = (lane>>4)*4 + reg = unit
#pragma unroll
      for (int gg = 0; gg < 4; ++gg) {
        f32x4 acc = aA[gg] + aBC[gg];
        *(f32x4*)&gl2[((wv * 4 + gg) * 16 + (lane & 15)) * 20 + (lane >> 4) * 4] = acc;
      }
    }
    __syncthreads();

    if (act) {
      // ---- fused cell: tree-sum the 4 waves' K-partials ----
#define GL2(w_,g_) gl2[(((w_) * 4 + (g_)) * 16 + cb) * 20 + cu]
      const float vi = ((GL2(0,0)+GL2(1,0)) + (GL2(2,0)+GL2(3,0))) + bi;
      const float vf = ((GL2(0,1)+GL2(1,1)) + (GL2(2,1)+GL2(3,1))) + bf_;
      const float vg = ((GL2(0,2)+GL2(1,2)) + (GL2(2,2)+GL2(3,2))) + bg;
      const float vo = ((GL2(0,3)+GL2(1,3)) + (GL2(2,3)+GL2(3,3))) + bo;
#undef GL2
      float cn = sigf(vf) * c_reg + sigf(vi) * tanhf(vg);
      float hn = sigf(vo) * tanhf(cn);
      if (tk == 1) { cn = c_reg; hn = h_reg; }
      c_reg = cn; h_reg = hn;
      const unsigned short hh = f2bf(hn);
      const unsigned short hl = f2bf(hn - bf2f(hh));
      const size_t hix = (size_t)(dl * 2 + (par ^ 1)) * BH + (size_t)(b0 + cb) * NH + uG;
      ast(p.hpk + hix, (unsigned)hh | ((unsigned)hl << 16));
      if (layer == 1) {
        // ordered by the full device barrier per step; partner prefetched (ii)
        const float v = dir ? (0.5f * hn) : hn;
        astf(p.out + oi, do_add ? (out_pf + v) : v);
      }
    }

    tk = tk_nx; tk_st = tk_st_nx;

    // ---- flat leader device barrier (r6 verbatim) ----
    __syncthreads();   // drains vmcnt -> all sc1 stores acked at coherence point
    if (tid == 0)
      ast(p.flags + (size_t)bid * 16, (unsigned)(j + 1));

    // (iii) issue next-step emb loads NOW; they fly during the gen-wait.
    if (do_epf && (j + 1 < SEQ)) {
      const float* e = p.emb + (size_t)tk_st * NH + ks;
#pragma unroll
      for (int q = 0; q < 16; ++q) epf[q] = *(const float4*)(e + q * 4);
    }

    if (bid == 0) {
      unsigned* f = p.flags + (size_t)tid * 16;
      while (ald(f) < (unsigned)(j + 1)) __builtin_amdgcn_s_sleep(1);
      __syncthreads();
      if (tid == 0) ast(p.gen, (unsigned)(j + 1));
    } else {
      if (tid < 64) {
        while (ald(p.gen) < (unsigned)(j + 1)) __builtin_amdgcn_s_sleep(1);
      }
      __syncthreads();
    }
  }

  // ---- epilogue: backward final carries bh1,bc1,bh2,bc2 ----
  if (dl == 2) {
    p.out[(size_t)SEQ * BH + 0 * (size_t)BH + (size_t)(b0 + cb) * NH + uG] = h_reg;
    p.out[(size_t)SEQ * BH + 1 * (size_t)BH + (size_t)(b0 + cb) * NH + uG] = c_reg;
  } else if (dl == 3) {
    p.out[(size_t)SEQ * BH + 2 * (size_t)BH + (size_t)(b0 + cb) * NH + uG] = h_reg;
    p.out[(size_t)SEQ * BH + 3 * (size_t)BH + (size_t)(b0 + cb) * NH + uG] = c_reg;
  }
}

extern "C" void kernel_launch(void* const* d_in, const int* in_sizes, int n_in,
                              void* d_out, int out_size, void* d_ws, size_t ws_size,
                              hipStream_t stream) {
  P p;
  p.word = (const int*)d_in[0];
  p.emb  = (const float*)d_in[1];
  for (int i = 0; i < 4; ++i) {
    p.Wih[i] = (const float*)d_in[2 + i * 4 + 0];
    p.Whh[i] = (const float*)d_in[2 + i * 4 + 1];
    p.bih[i] = (const float*)d_in[2 + i * 4 + 2];
    p.bhh[i] = (const float*)d_in[2 + i * 4 + 3];
  }
  unsigned char* ws = (unsigned char*)d_ws;
  p.flags = (unsigned*)ws;                       // 16 KB (256 x 64B slots)
  p.gen   = (unsigned*)(ws + 16384);             // one 64B line
  p.hpk   = (unsigned*)(ws + 16448);             // 512 KB packed h
  p.out   = (float*)d_out;

  hipMemsetAsync(d_ws, 0, 16448 + (size_t)8 * BH * 4, stream);

  // used: 32*KP*2 + 4*4*16*20*4 = 86528 B; request 88 KB to keep 1 block/CU
  const int smem = 90112;
  hipFuncSetAttribute(reinterpret_cast<const void*>(enc_persist),
                      hipFuncAttributeMaxDynamicSharedMemorySize, smem);
  hipLaunchKernelGGL(enc_persist, dim3(256), dim3(256), smem, stream, p);
}

// Round 8
// 5082.312 us; speedup vs baseline: 3.0460x; 2.1328x over previous
//
#include <hip/hip_runtime.h>
#include <math.h>

// EncoderRNN persistent kernel, round 13 = round 12 (PASSING, 10.84ms) + ONE
// structural change: COALESCED slab staging for the agent-coherent h reads.
// Old stage_h_slice: thread (rb,sr) reads its own 256B blocked -> per load
// instruction the 64 lanes span 2KB/256B strides -> 64 lines touched per 8B
// instr, 2048 line-transactions per wave-pair for 256 lines of data (8x
// redundant), serialized at the coherence point right after barrier release.
// New stage_slab: the block's 16 batch rows are 32KB CONTIGUOUS in hpk ->
// wave-pair lanes sweep linearly (instr q: lane L reads u64 slab[L+128q]) =
// 64 consecutive u64 = 8 fully-consumed lines/instr, 256 transactions total.
// Same ald64 width/count per thread, bit-identical unpack math, LDS writes
// 4B at +4L = 2-way bank alias (free, m136). Applied to recurrent half
// (waves 2-3) and layer2 x-half (waves 0-1); layer0 emb keeps r12 prefetch.
// Everything else r12 verbatim (barrier, out prefetch, MFMA, cell).
// Predicted: pass, absmax 0.0001220703, dur 10.84 -> ~8.6-9.8ms,
// bank-conflict ~1.0e8 unchanged, FETCH/WRITE unchanged.

#define SEQ 1024
#define NB 32
#define NH 512
#define BH (NB*NH)
#define KP 1032   // LDS row stride in shorts = 2064 B (odd 16B slots)

typedef __attribute__((ext_vector_type(8))) short short8;
typedef __attribute__((ext_vector_type(4))) float f32x4;
typedef unsigned long long u64;

struct P {
  const int*   word;
  const float* emb;
  const float* Wih[4];   // dl = dir*2+layer: 0=fwd1,1=fwd2,2=bwd1,3=bwd2
  const float* Whh[4];
  const float* bih[4];
  const float* bhh[4];
  unsigned* flags;       // 256 slots, stride 16 u32 (one 64B line each)
  unsigned* gen;         // single 64B line
  unsigned* hpk;         // [4 dl][2 par][NB][NH] u32 = (bf16hi | bf16lo<<16)
  float* out;
};

__device__ __forceinline__ unsigned short f2bf(float x) {
  unsigned u = __float_as_uint(x);
  return (unsigned short)((u + 0x7fffu + ((u >> 16) & 1u)) >> 16);  // RNE
}
__device__ __forceinline__ float bf2f(unsigned short b) {
  return __uint_as_float(((unsigned)b) << 16);
}
__device__ __forceinline__ float sigf(float x) { return 1.0f / (1.0f + expf(-x)); }

__device__ __forceinline__ unsigned ald(const unsigned* p_) {
  return __hip_atomic_load((unsigned*)p_, __ATOMIC_RELAXED, __HIP_MEMORY_SCOPE_AGENT);
}
__device__ __forceinline__ u64 ald64(const u64* p_) {
  return __hip_atomic_load((u64*)p_, __ATOMIC_RELAXED, __HIP_MEMORY_SCOPE_AGENT);
}
__device__ __forceinline__ void ast(unsigned* p_, unsigned v) {
  __hip_atomic_store(p_, v, __ATOMIC_RELAXED, __HIP_MEMORY_SCOPE_AGENT);
}
__device__ __forceinline__ float aldf(const float* p_) {
  return __hip_atomic_load((float*)p_, __ATOMIC_RELAXED, __HIP_MEMORY_SCOPE_AGENT);
}
__device__ __forceinline__ void astf(float* p_, float v) {
  __hip_atomic_store(p_, v, __ATOMIC_RELAXED, __HIP_MEMORY_SCOPE_AGENT);
}

// Coalesced slab stage: a wave-PAIR (128 lanes) reads a 32KB contiguous slab
// (16 batch rows x 512 packed u32) and writes bf16 hi/lo planes into LDS at
// k-range [koff, koff+512). Instr q: lane Lpair reads u64 slab64[Lpair+128q]
// (64 consecutive u64 per wave = 8 fully-consumed 64B lines). Unpack math is
// bit-identical to the old stage_h_slice (w0=even unit, w1=odd unit).
__device__ __forceinline__ void stage_slab(const unsigned* slab,
                                           unsigned short* xhHi,
                                           unsigned short* xhLo,
                                           int Lpair, int koff) {
  const u64* s64 = (const u64*)slab;
  u64 A[32];
#pragma unroll
  for (int q = 0; q < 32; ++q) A[q] = ald64(s64 + Lpair + q * 128);
#pragma unroll
  for (int q = 0; q < 32; ++q) {
    const int r = q >> 1;                    // batch row 0..15
    const int c = (q & 1) * 128 + Lpair;     // u64 col 0..255 -> units 2c,2c+1
    const unsigned w0 = (unsigned)A[q];
    const unsigned w1 = (unsigned)(A[q] >> 32);
    *(unsigned*)(xhHi + r * KP + koff + 2 * c) = (w0 & 0xffffu) | (w1 << 16);
    *(unsigned*)(xhLo + r * KP + koff + 2 * c) = (w0 >> 16)     | (w1 & 0xffff0000u);
  }
}

__global__ __launch_bounds__(256, 1) void enc_persist(P p) {
  extern __shared__ unsigned short smem[];
  unsigned short* xhHi = smem;              // [16][KP]
  unsigned short* xhLo = smem + 16 * KP;    // [16][KP]
  float* gl2 = (float*)(smem + 32 * KP);    // [4 wv][4 gate][16 batch][20] fp32

  const int tid  = threadIdx.x;
  const int bid  = blockIdx.x;
  const int dl   = bid >> 6;
  const int dir  = dl >> 1, layer = dl & 1;
  const int r6   = bid & 63;
  const int u0   = (r6 >> 1) * 16;   // 32 unit-groups of 16
  const int b0   = (r6 & 1) * 16;    // 2 batch-halves of 16
  const int lane = tid & 63, wv = tid >> 6;   // wave wv owns kc in [8wv, 8wv+8)

  // ---- prologue: W fragments (bf16 hi/lo) for all 4 gates, this wave's K ----
  short8 aHi[32], aLo[32];   // index gg*8+kk
  {
    const int kg = (lane >> 4) * 8;
#pragma unroll
    for (int gg = 0; gg < 4; ++gg) {
      const int gr = gg * 512 + u0 + (lane & 15);   // global gate row
      const float* Wi = p.Wih[dl] + (size_t)gr * NH;
      const float* Wh = p.Whh[dl] + (size_t)gr * NH;
#pragma unroll
      for (int kk = 0; kk < 8; ++kk) {
        const int k0 = (wv * 8 + kk) * 32 + kg;
        const float* s = (k0 < 512) ? (Wi + k0) : (Wh + (k0 - 512));
        float4 v0 = *(const float4*)s;
        float4 v1 = *(const float4*)(s + 4);
        float xs[8] = {v0.x, v0.y, v0.z, v0.w, v1.x, v1.y, v1.z, v1.w};
        short8 h8, l8;
#pragma unroll
        for (int q = 0; q < 8; ++q) {
          unsigned short hb = f2bf(xs[q]);
          h8[q] = (short)hb;
          l8[q] = (short)f2bf(xs[q] - bf2f(hb));
        }
        aHi[gg * 8 + kk] = h8; aLo[gg * 8 + kk] = l8;
      }
    }
  }

  // cell thread mapping: cb = batch-local (tid>>4), cu = unit (tid&15)
  const int cu = tid & 15, cb = tid >> 4;
  const int uG = u0 + cu;
  const float bi  = p.bih[dl][uG]        + p.bhh[dl][uG];
  const float bf_ = p.bih[dl][512 + uG]  + p.bhh[dl][512 + uG];
  const float bg  = p.bih[dl][1024 + uG] + p.bhh[dl][1024 + uG];
  const float bo  = p.bih[dl][1536 + uG] + p.bhh[dl][1536 + uG];

  float c_reg = 0.f, h_reg = 0.f;

  // emb staging thread mapping (layer0 waves 0-1): rb = row, sr = k-slice
  const int sr = tid >> 4;
  const int rb = tid & 15;
  const int ks = sr * 64;      // this thread's 64-short slice of the row

  int tk, tk_st;
  {
    const int to0 = dir ? (SEQ - 1) : 0;
    tk    = p.word[(size_t)to0 * NB + b0 + cb];   // cell mask token
    tk_st = p.word[(size_t)to0 * NB + b0 + rb];   // staging-row token
  }

  // emb prefetch registers (r12 (iii)): layer-0 blocks, waves 0-1 only.
  const bool do_epf = (layer == 0) && (sr < 8);
  float4 epf[16];
  if (do_epf) {   // prologue prefetch for j=0
    const float* e = p.emb + (size_t)tk_st * NH + ks;
#pragma unroll
    for (int q = 0; q < 16; ++q) epf[q] = *(const float4*)(e + q * 4);
  }

  for (int j = 0; j <= SEQ; ++j) {
    const int act = layer ? (j >= 1) : (j < SEQ);
    const int t = layer ? (j - 1) : j;
    const int torig = dir ? (SEQ - 1 - t) : t;
    const int par = j & 1;

    if (act) {
      // ---- stage one row-slice of [x(512);h(512)] bf16 hi/lo into LDS ----
      if (wv < 2) {   // x-part, k in [0,512)  (wave-pair 0, uniform)
        if (layer == 0) {  // convert prefetched emb registers (same RNE math)
#pragma unroll
          for (int h2 = 0; h2 < 2; ++h2) {
#pragma unroll
            for (int q = 0; q < 4; ++q) {
              const float4 va = epf[h2 * 8 + 2 * q];
              const float4 vb = epf[h2 * 8 + 2 * q + 1];
              float xs[8] = {va.x, va.y, va.z, va.w, vb.x, vb.y, vb.z, vb.w};
              unsigned hw[4], lw[4];
#pragma unroll
              for (int m = 0; m < 4; ++m) {
                unsigned short ha = f2bf(xs[2*m]);
                unsigned short hc = f2bf(xs[2*m+1]);
                unsigned short la = f2bf(xs[2*m]   - bf2f(ha));
                unsigned short lc = f2bf(xs[2*m+1] - bf2f(hc));
                hw[m] = (unsigned)ha | ((unsigned)hc << 16);
                lw[m] = (unsigned)la | ((unsigned)lc << 16);
              }
              uint4 hv, lv;
              hv.x=hw[0]; hv.y=hw[1]; hv.z=hw[2]; hv.w=hw[3];
              lv.x=lw[0]; lv.y=lw[1]; lv.z=lw[2]; lv.w=lw[3];
              *(uint4*)(xhHi + rb * KP + ks + h2 * 32 + q * 8) = hv;
              *(uint4*)(xhLo + rb * KP + ks + h2 * 32 + q * 8) = lv;
            }
          }
        } else {      // layer2 x = layer1 h: coalesced 32KB slab read
          const unsigned* slab = p.hpk + (size_t)((dl - 1) * 2 + par) * BH
                                       + (size_t)b0 * NH;
          stage_slab(slab, xhHi, xhLo, tid, 0);
        }
      } else {        // recurrent half, k in [512,1024)  (wave-pair 1, uniform)
        const unsigned* slab = p.hpk + (size_t)(dl * 2 + par) * BH
                                     + (size_t)b0 * NH;
        stage_slab(slab, xhHi, xhLo, tid - 128, 512);
      }
    }

    // prefetch next step's tokens (latency hides under MFMA+cell+barrier)
    int tk_nx = tk, tk_st_nx = tk_st;
    if (j < SEQ) {
      int t_nx = layer ? j : (j + 1);
      if (t_nx > SEQ - 1) t_nx = SEQ - 1;
      const int to_nx = dir ? (SEQ - 1 - t_nx) : t_nx;
      tk_nx    = p.word[(size_t)to_nx * NB + b0 + cb];
      tk_st_nx = p.word[(size_t)to_nx * NB + b0 + rb];
    }

    // out-partner prefetch (r12 (ii)): partner written >=1 epoch ago.
    float out_pf = 0.f;
    size_t oi = 0;
    int do_add = 0;
    if (act && layer == 1) {
      oi = (size_t)torig * BH + (size_t)(b0 + cb) * NH + uG;
      do_add = dir ? (torig < 512) : (torig > 511);
      if (do_add) out_pf = aldf(p.out + oi);
    }

    __syncthreads();

    if (act) {
      // ---- K-split MFMA: wave wv sums kc in [8wv,8wv+8) for all 4 gates ----
      f32x4 aA[4], aBC[4];
#pragma unroll
      for (int gg = 0; gg < 4; ++gg) {
        aA[gg]  = (f32x4){0.f, 0.f, 0.f, 0.f};
        aBC[gg] = (f32x4){0.f, 0.f, 0.f, 0.f};
      }
      const unsigned short* bp = xhHi + (lane & 15) * KP + (lane >> 4) * 8;
      const unsigned short* bq = xhLo + (lane & 15) * KP + (lane >> 4) * 8;
#pragma unroll
      for (int kk = 0; kk < 8; ++kk) {
        const int kc = wv * 8 + kk;
        short8 bH = *(const short8*)(bp + kc * 32);
        short8 bL = *(const short8*)(bq + kc * 32);
#pragma unroll
        for (int gg = 0; gg < 4; ++gg) {
          aA[gg]  = __builtin_amdgcn_mfma_f32_16x16x32_bf16(aHi[gg*8+kk], bH, aA[gg],  0, 0, 0);
          aBC[gg] = __builtin_amdgcn_mfma_f32_16x16x32_bf16(aLo[gg*8+kk], bH, aBC[gg], 0, 0, 0);
          aBC[gg] = __builtin_amdgcn_mfma_f32_16x16x32_bf16(aHi[gg*8+kk], bL, aBC[gg], 0, 0, 0);
        }
      }
      // C/D (m89): col = lane&15 = batch, row = (lane>>4)*4 + reg = unit
#pragma unroll
      for (int gg = 0; gg < 4; ++gg) {
        f32x4 acc = aA[gg] + aBC[gg];
        *(f32x4*)&gl2[((wv * 4 + gg) * 16 + (lane & 15)) * 20 + (lane >> 4) * 4] = acc;
      }
    }
    __syncthreads();

    if (act) {
      // ---- fused cell: tree-sum the 4 waves' K-partials ----
#define GL2(w_,g_) gl2[(((w_) * 4 + (g_)) * 16 + cb) * 20 + cu]
      const float vi = ((GL2(0,0)+GL2(1,0)) + (GL2(2,0)+GL2(3,0))) + bi;
      const float vf = ((GL2(0,1)+GL2(1,1)) + (GL2(2,1)+GL2(3,1))) + bf_;
      const float vg = ((GL2(0,2)+GL2(1,2)) + (GL2(2,2)+GL2(3,2))) + bg;
      const float vo = ((GL2(0,3)+GL2(1,3)) + (GL2(2,3)+GL2(3,3))) + bo;
#undef GL2
      float cn = sigf(vf) * c_reg + sigf(vi) * tanhf(vg);
      float hn = sigf(vo) * tanhf(cn);
      if (tk == 1) { cn = c_reg; hn = h_reg; }
      c_reg = cn; h_reg = hn;
      const unsigned short hh = f2bf(hn);
      const unsigned short hl = f2bf(hn - bf2f(hh));
      const size_t hix = (size_t)(dl * 2 + (par ^ 1)) * BH + (size_t)(b0 + cb) * NH + uG;
      ast(p.hpk + hix, (unsigned)hh | ((unsigned)hl << 16));
      if (layer == 1) {
        // ordered by the full device barrier per step; partner prefetched
        const float v = dir ? (0.5f * hn) : hn;
        astf(p.out + oi, do_add ? (out_pf + v) : v);
      }
    }

    tk = tk_nx; tk_st = tk_st_nx;

    // ---- flat leader device barrier (r6 verbatim) ----
    __syncthreads();   // drains vmcnt -> all sc1 stores acked at coherence point
    if (tid == 0)
      ast(p.flags + (size_t)bid * 16, (unsigned)(j + 1));

    // issue next-step emb loads NOW; they fly during the gen-wait (r12 (iii))
    if (do_epf && (j + 1 < SEQ)) {
      const float* e = p.emb + (size_t)tk_st * NH + ks;
#pragma unroll
      for (int q = 0; q < 16; ++q) epf[q] = *(const float4*)(e + q * 4);
    }

    if (bid == 0) {
      unsigned* f = p.flags + (size_t)tid * 16;
      while (ald(f) < (unsigned)(j + 1)) __builtin_amdgcn_s_sleep(1);
      __syncthreads();
      if (tid == 0) ast(p.gen, (unsigned)(j + 1));
    } else {
      if (tid < 64) {
        while (ald(p.gen) < (unsigned)(j + 1)) __builtin_amdgcn_s_sleep(1);
      }
      __syncthreads();
    }
  }

  // ---- epilogue: backward final carries bh1,bc1,bh2,bc2 ----
  if (dl == 2) {
    p.out[(size_t)SEQ * BH + 0 * (size_t)BH + (size_t)(b0 + cb) * NH + uG] = h_reg;
    p.out[(size_t)SEQ * BH + 1 * (size_t)BH + (size_t)(b0 + cb) * NH + uG] = c_reg;
  } else if (dl == 3) {
    p.out[(size_t)SEQ * BH + 2 * (size_t)BH + (size_t)(b0 + cb) * NH + uG] = h_reg;
    p.out[(size_t)SEQ * BH + 3 * (size_t)BH + (size_t)(b0 + cb) * NH + uG] = c_reg;
  }
}

extern "C" void kernel_launch(void* const* d_in, const int* in_sizes, int n_in,
                              void* d_out, int out_size, void* d_ws, size_t ws_size,
                              hipStream_t stream) {
  P p;
  p.word = (const int*)d_in[0];
  p.emb  = (const float*)d_in[1];
  for (int i = 0; i < 4; ++i) {
    p.Wih[i] = (const float*)d_in[2 + i * 4 + 0];
    p.Whh[i] = (const float*)d_in[2 + i * 4 + 1];
    p.bih[i] = (const float*)d_in[2 + i * 4 + 2];
    p.bhh[i] = (const float*)d_in[2 + i * 4 + 3];
  }
  unsigned char* ws = (unsigned char*)d_ws;
  p.flags = (unsigned*)ws;                       // 16 KB (256 x 64B slots)
  p.gen   = (unsigned*)(ws + 16384);             // one 64B line
  p.hpk   = (unsigned*)(ws + 16448);             // 512 KB packed h
  p.out   = (float*)d_out;

  hipMemsetAsync(d_ws, 0, 16448 + (size_t)8 * BH * 4, stream);

  // used: 32*KP*2 + 4*4*16*20*4 = 86528 B; request 88 KB to keep 1 block/CU
  const int smem = 90112;
  hipFuncSetAttribute(reinterpret_cast<const void*>(enc_persist),
                      hipFuncAttributeMaxDynamicSharedMemorySize, smem);
  hipLaunchKernelGGL(enc_persist, dim3(256), dim3(256), smem, stream, p);
}

// Round 9
// 4759.164 us; speedup vs baseline: 3.2529x; 1.0679x over previous
//
#include <hip/hip_runtime.h>
#include <math.h>

// EncoderRNN persistent kernel, round 14 = round 13 (PASSING, 5.08ms) + ONE
// change: layer-0 x-staging consumes a PRE-PACKED bf16 emb table instead of
// converting fp32 on the fly.
// Rationale: r13's coalescing collapsed staging; the per-step max over blocks
// is now paced by layer-0's ~1150-VALU-op RNE convert (~1us on waves 0-1,
// exposed now that the step is 5us; in r9's 11us regime it was hidden).
//  - conv_embp (one-time): emb fp32 -> u32 (hh | hl<<16), IDENTICAL RNE split
//    math as the in-loop convert -> bit-exact staging values, absmax same.
//  - layer-0 x-staging: prefetch 16 uint4/thread from the packed table during
//    the barrier wait (r12's proven hiding slot; plain cached loads -- r9
//    proved kernel-boundary coherence for a ws emb table), then unpack to
//    LDS: ~130 VALU (8x fewer). Row-grouped mapping (8 lanes x 16B per row)
//    = 16 fully-consumed lines/instr (r9's plane gather was 64 lines/instr).
//  - ws-guarded; fallback = r13's float4-prefetch + convert path verbatim.
// Forensic note: r7/r8's (dir,b0) domain split failed because the fwd/bwd
// out-merge has only a 1-STEP skew margin at torig=511/512 -> independent
// domains can skew past it. Domain split stays retired.
// Predicted: pass, absmax 0.0001220703, dur 5.08 -> ~4.3-4.7ms (neutral if
// layer-2 staging is the real pacer), VALUBusy ~18, bank-conflict ~1.0e8.

#define SEQ 1024
#define NB 32
#define NH 512
#define BH (NB*NH)
#define NV 32000
#define KP 1032   // LDS row stride in shorts = 2064 B (odd 16B slots)

typedef __attribute__((ext_vector_type(8))) short short8;
typedef __attribute__((ext_vector_type(4))) float f32x4;
typedef unsigned long long u64;

struct P {
  const int*   word;
  const float* emb;
  const float* Wih[4];   // dl = dir*2+layer: 0=fwd1,1=fwd2,2=bwd1,3=bwd2
  const float* Whh[4];
  const float* bih[4];
  const float* bhh[4];
  unsigned* flags;       // 256 slots, stride 16 u32 (one 64B line each)
  unsigned* gen;         // single 64B line
  unsigned* hpk;         // [4 dl][2 par][NB][NH] u32 = (bf16hi | bf16lo<<16)
  const unsigned* embP;  // [NV][NH] u32 packed (hh | hl<<16), or null
  float* out;
};

__device__ __forceinline__ unsigned short f2bf(float x) {
  unsigned u = __float_as_uint(x);
  return (unsigned short)((u + 0x7fffu + ((u >> 16) & 1u)) >> 16);  // RNE
}
__device__ __forceinline__ float bf2f(unsigned short b) {
  return __uint_as_float(((unsigned)b) << 16);
}
__device__ __forceinline__ float sigf(float x) { return 1.0f / (1.0f + expf(-x)); }

__device__ __forceinline__ unsigned ald(const unsigned* p_) {
  return __hip_atomic_load((unsigned*)p_, __ATOMIC_RELAXED, __HIP_MEMORY_SCOPE_AGENT);
}
__device__ __forceinline__ u64 ald64(const u64* p_) {
  return __hip_atomic_load((u64*)p_, __ATOMIC_RELAXED, __HIP_MEMORY_SCOPE_AGENT);
}
__device__ __forceinline__ void ast(unsigned* p_, unsigned v) {
  __hip_atomic_store(p_, v, __ATOMIC_RELAXED, __HIP_MEMORY_SCOPE_AGENT);
}
__device__ __forceinline__ float aldf(const float* p_) {
  return __hip_atomic_load((float*)p_, __ATOMIC_RELAXED, __HIP_MEMORY_SCOPE_AGENT);
}
__device__ __forceinline__ void astf(float* p_, float v) {
  __hip_atomic_store(p_, v, __ATOMIC_RELAXED, __HIP_MEMORY_SCOPE_AGENT);
}

// Coalesced slab stage (r13): wave-PAIR (128 lanes) reads a 32KB contiguous
// slab (16 rows x 512 packed u32) -> bf16 hi/lo planes in LDS at [koff,+512).
__device__ __forceinline__ void stage_slab(const unsigned* slab,
                                           unsigned short* xhHi,
                                           unsigned short* xhLo,
                                           int Lpair, int koff) {
  const u64* s64 = (const u64*)slab;
  u64 A[32];
#pragma unroll
  for (int q = 0; q < 32; ++q) A[q] = ald64(s64 + Lpair + q * 128);
#pragma unroll
  for (int q = 0; q < 32; ++q) {
    const int r = q >> 1;                    // batch row 0..15
    const int c = (q & 1) * 128 + Lpair;     // u64 col 0..255 -> units 2c,2c+1
    const unsigned w0 = (unsigned)A[q];
    const unsigned w1 = (unsigned)(A[q] >> 32);
    *(unsigned*)(xhHi + r * KP + koff + 2 * c) = (w0 & 0xffffu) | (w1 << 16);
    *(unsigned*)(xhLo + r * KP + koff + 2 * c) = (w0 >> 16)     | (w1 & 0xffff0000u);
  }
}

// one-time embedding fp32 -> packed u32 (hh | hl<<16); identical RNE math
__global__ void conv_embp(const float* __restrict__ e,
                          unsigned* __restrict__ pk) {
  const size_t i = ((size_t)blockIdx.x * 256 + threadIdx.x) * 8;
  float4 a = *(const float4*)(e + i);
  float4 b = *(const float4*)(e + i + 4);
  float xs[8] = {a.x, a.y, a.z, a.w, b.x, b.y, b.z, b.w};
  unsigned o[8];
#pragma unroll
  for (int q = 0; q < 8; ++q) {
    unsigned short hb = f2bf(xs[q]);
    unsigned short lb = f2bf(xs[q] - bf2f(hb));
    o[q] = (unsigned)hb | ((unsigned)lb << 16);
  }
  uint4 v0, v1;
  v0.x=o[0]; v0.y=o[1]; v0.z=o[2]; v0.w=o[3];
  v1.x=o[4]; v1.y=o[5]; v1.z=o[6]; v1.w=o[7];
  *(uint4*)(pk + i)     = v0;
  *(uint4*)(pk + i + 4) = v1;
}

__global__ __launch_bounds__(256, 1) void enc_persist(P p) {
  extern __shared__ unsigned short smem[];
  unsigned short* xhHi = smem;              // [16][KP]
  unsigned short* xhLo = smem + 16 * KP;    // [16][KP]
  float* gl2 = (float*)(smem + 32 * KP);    // [4 wv][4 gate][16 batch][20] fp32

  const int tid  = threadIdx.x;
  const int bid  = blockIdx.x;
  const int dl   = bid >> 6;
  const int dir  = dl >> 1, layer = dl & 1;
  const int r6   = bid & 63;
  const int u0   = (r6 >> 1) * 16;   // 32 unit-groups of 16
  const int b0   = (r6 & 1) * 16;    // 2 batch-halves of 16
  const int lane = tid & 63, wv = tid >> 6;   // wave wv owns kc in [8wv, 8wv+8)

  // ---- prologue: W fragments (bf16 hi/lo) for all 4 gates, this wave's K ----
  short8 aHi[32], aLo[32];   // index gg*8+kk
  {
    const int kg = (lane >> 4) * 8;
#pragma unroll
    for (int gg = 0; gg < 4; ++gg) {
      const int gr = gg * 512 + u0 + (lane & 15);   // global gate row
      const float* Wi = p.Wih[dl] + (size_t)gr * NH;
      const float* Wh = p.Whh[dl] + (size_t)gr * NH;
#pragma unroll
      for (int kk = 0; kk < 8; ++kk) {
        const int k0 = (wv * 8 + kk) * 32 + kg;
        const float* s = (k0 < 512) ? (Wi + k0) : (Wh + (k0 - 512));
        float4 v0 = *(const float4*)s;
        float4 v1 = *(const float4*)(s + 4);
        float xs[8] = {v0.x, v0.y, v0.z, v0.w, v1.x, v1.y, v1.z, v1.w};
        short8 h8, l8;
#pragma unroll
        for (int q = 0; q < 8; ++q) {
          unsigned short hb = f2bf(xs[q]);
          h8[q] = (short)hb;
          l8[q] = (short)f2bf(xs[q] - bf2f(hb));
        }
        aHi[gg * 8 + kk] = h8; aLo[gg * 8 + kk] = l8;
      }
    }
  }

  // cell thread mapping: cb = batch-local (tid>>4), cu = unit (tid&15)
  const int cu = tid & 15, cb = tid >> 4;
  const int uG = u0 + cu;
  const float bi  = p.bih[dl][uG]        + p.bhh[dl][uG];
  const float bf_ = p.bih[dl][512 + uG]  + p.bhh[dl][512 + uG];
  const float bg  = p.bih[dl][1024 + uG] + p.bhh[dl][1024 + uG];
  const float bo  = p.bih[dl][1536 + uG] + p.bhh[dl][1536 + uG];

  float c_reg = 0.f, h_reg = 0.f;

  // legacy emb staging mapping (fallback path): rb = row, sr = k-slice
  const int sr = tid >> 4;
  const int rb = tid & 15;
  const int ks = sr * 64;

  // packed emb staging mapping (waves 0-1): rp = row (tid>>3), lp = tid&7
  const int rp = tid >> 3;     // 0..15 for tid<128
  const int lp = tid & 7;

  int tk, tk_st, tk_pk;
  {
    const int to0 = dir ? (SEQ - 1) : 0;
    tk    = p.word[(size_t)to0 * NB + b0 + cb];   // cell mask token
    tk_st = p.word[(size_t)to0 * NB + b0 + rb];   // fallback staging token
    tk_pk = p.word[(size_t)to0 * NB + b0 + (rp & 15)]; // packed staging token
  }

  const bool use_pk = (layer == 0) && (tid < 128) && (p.embP != nullptr);
  const bool do_epf = (layer == 0) && (sr < 8) && (p.embP == nullptr);
  union { float4 f[16]; uint4 u[16]; } epr;
  if (use_pk) {   // prologue prefetch for j=0 (packed)
    const uint4* src = (const uint4*)(p.embP + (size_t)tk_pk * NH);
#pragma unroll
    for (int q = 0; q < 16; ++q) epr.u[q] = src[lp + q * 8];
  } else if (do_epf) {  // prologue prefetch for j=0 (fallback fp32)
    const float* e = p.emb + (size_t)tk_st * NH + ks;
#pragma unroll
    for (int q = 0; q < 16; ++q) epr.f[q] = *(const float4*)(e + q * 4);
  }

  for (int j = 0; j <= SEQ; ++j) {
    const int act = layer ? (j >= 1) : (j < SEQ);
    const int t = layer ? (j - 1) : j;
    const int torig = dir ? (SEQ - 1 - t) : t;
    const int par = j & 1;

    if (act) {
      // ---- stage one row-slice of [x(512);h(512)] bf16 hi/lo into LDS ----
      if (wv < 2) {   // x-part, k in [0,512)  (wave-pair 0, uniform)
        if (layer == 0) {
          if (p.embP) {
            // unpack prefetched packed-emb registers -> LDS (bit-exact)
#pragma unroll
            for (int q = 0; q < 16; ++q) {
              const uint4 w = epr.u[q];
              const int u = 4 * (lp + q * 8);   // unit 0..508
              uint2 hv, lv;
              hv.x = (w.x & 0xffffu) | (w.y << 16);
              hv.y = (w.z & 0xffffu) | (w.w << 16);
              lv.x = (w.x >> 16)     | (w.y & 0xffff0000u);
              lv.y = (w.z >> 16)     | (w.w & 0xffff0000u);
              *(uint2*)(xhHi + rp * KP + u) = hv;
              *(uint2*)(xhLo + rp * KP + u) = lv;
            }
          } else {  // fallback: convert prefetched fp32 regs (r13 verbatim)
#pragma unroll
            for (int h2 = 0; h2 < 2; ++h2) {
#pragma unroll
              for (int q = 0; q < 4; ++q) {
                const float4 va = epr.f[h2 * 8 + 2 * q];
                const float4 vb = epr.f[h2 * 8 + 2 * q + 1];
                float xs[8] = {va.x, va.y, va.z, va.w, vb.x, vb.y, vb.z, vb.w};
                unsigned hw[4], lw[4];
#pragma unroll
                for (int m = 0; m < 4; ++m) {
                  unsigned short ha = f2bf(xs[2*m]);
                  unsigned short hc = f2bf(xs[2*m+1]);
                  unsigned short la = f2bf(xs[2*m]   - bf2f(ha));
                  unsigned short lc = f2bf(xs[2*m+1] - bf2f(hc));
                  hw[m] = (unsigned)ha | ((unsigned)hc << 16);
                  lw[m] = (unsigned)la | ((unsigned)lc << 16);
                }
                uint4 hv, lv;
                hv.x=hw[0]; hv.y=hw[1]; hv.z=hw[2]; hv.w=hw[3];
                lv.x=lw[0]; lv.y=lw[1]; lv.z=lw[2]; lv.w=lw[3];
                *(uint4*)(xhHi + rb * KP + ks + h2 * 32 + q * 8) = hv;
                *(uint4*)(xhLo + rb * KP + ks + h2 * 32 + q * 8) = lv;
              }
            }
          }
        } else {      // layer2 x = layer1 h: coalesced 32KB slab read
          const unsigned* slab = p.hpk + (size_t)((dl - 1) * 2 + par) * BH
                                       + (size_t)b0 * NH;
          stage_slab(slab, xhHi, xhLo, tid, 0);
        }
      } else {        // recurrent half, k in [512,1024)  (wave-pair 1, uniform)
        const unsigned* slab = p.hpk + (size_t)(dl * 2 + par) * BH
                                     + (size_t)b0 * NH;
        stage_slab(slab, xhHi, xhLo, tid - 128, 512);
      }
    }

    // prefetch next step's tokens (latency hides under MFMA+cell+barrier)
    int tk_nx = tk, tk_st_nx = tk_st, tk_pk_nx = tk_pk;
    if (j < SEQ) {
      int t_nx = layer ? j : (j + 1);
      if (t_nx > SEQ - 1) t_nx = SEQ - 1;
      const int to_nx = dir ? (SEQ - 1 - t_nx) : t_nx;
      tk_nx    = p.word[(size_t)to_nx * NB + b0 + cb];
      tk_st_nx = p.word[(size_t)to_nx * NB + b0 + rb];
      tk_pk_nx = p.word[(size_t)to_nx * NB + b0 + (rp & 15)];
    }

    // out-partner prefetch (r12 (ii)): partner written >=1 epoch ago.
    float out_pf = 0.f;
    size_t oi = 0;
    int do_add = 0;
    if (act && layer == 1) {
      oi = (size_t)torig * BH + (size_t)(b0 + cb) * NH + uG;
      do_add = dir ? (torig < 512) : (torig > 511);
      if (do_add) out_pf = aldf(p.out + oi);
    }

    __syncthreads();

    if (act) {
      // ---- K-split MFMA: wave wv sums kc in [8wv,8wv+8) for all 4 gates ----
      f32x4 aA[4], aBC[4];
#pragma unroll
      for (int gg = 0; gg < 4; ++gg) {
        aA[gg]  = (f32x4){0.f, 0.f, 0.f, 0.f};
        aBC[gg] = (f32x4){0.f, 0.f, 0.f, 0.f};
      }
      const unsigned short* bp = xhHi + (lane & 15) * KP + (lane >> 4) * 8;
      const unsigned short* bq = xhLo + (lane & 15) * KP + (lane >> 4) * 8;
#pragma unroll
      for (int kk = 0; kk < 8; ++kk) {
        const int kc = wv * 8 + kk;
        short8 bH = *(const short8*)(bp + kc * 32);
        short8 bL = *(const short8*)(bq + kc * 32);
#pragma unroll
        for (int gg = 0; gg < 4; ++gg) {
          aA[gg]  = __builtin_amdgcn_mfma_f32_16x16x32_bf16(aHi[gg*8+kk], bH, aA[gg],  0, 0, 0);
          aBC[gg] = __builtin_amdgcn_mfma_f32_16x16x32_bf16(aLo[gg*8+kk], bH, aBC[gg], 0, 0, 0);
          aBC[gg] = __builtin_amdgcn_mfma_f32_16x16x32_bf16(aHi[gg*8+kk], bL, aBC[gg], 0, 0, 0);
        }
      }
      // C/D (m89): col = lane&15 = batch, row = (lane>>4)*4 + reg = unit
#pragma unroll
      for (int gg = 0; gg < 4; ++gg) {
        f32x4 acc = aA[gg] + aBC[gg];
        *(f32x4*)&gl2[((wv * 4 + gg) * 16 + (lane & 15)) * 20 + (lane >> 4) * 4] = acc;
      }
    }
    __syncthreads();

    if (act) {
      // ---- fused cell: tree-sum the 4 waves' K-partials ----
#define GL2(w_,g_) gl2[(((w_) * 4 + (g_)) * 16 + cb) * 20 + cu]
      const float vi = ((GL2(0,0)+GL2(1,0)) + (GL2(2,0)+GL2(3,0))) + bi;
      const float vf = ((GL2(0,1)+GL2(1,1)) + (GL2(2,1)+GL2(3,1))) + bf_;
      const float vg = ((GL2(0,2)+GL2(1,2)) + (GL2(2,2)+GL2(3,2))) + bg;
      const float vo = ((GL2(0,3)+GL2(1,3)) + (GL2(2,3)+GL2(3,3))) + bo;
#undef GL2
      float cn = sigf(vf) * c_reg + sigf(vi) * tanhf(vg);
      float hn = sigf(vo) * tanhf(cn);
      if (tk == 1) { cn = c_reg; hn = h_reg; }
      c_reg = cn; h_reg = hn;
      const unsigned short hh = f2bf(hn);
      const unsigned short hl = f2bf(hn - bf2f(hh));
      const size_t hix = (size_t)(dl * 2 + (par ^ 1)) * BH + (size_t)(b0 + cb) * NH + uG;
      ast(p.hpk + hix, (unsigned)hh | ((unsigned)hl << 16));
      if (layer == 1) {
        // ordered by the full device barrier per step; partner prefetched
        const float v = dir ? (0.5f * hn) : hn;
        astf(p.out + oi, do_add ? (out_pf + v) : v);
      }
    }

    tk = tk_nx; tk_st = tk_st_nx; tk_pk = tk_pk_nx;

    // ---- flat leader device barrier (r6 verbatim) ----
    __syncthreads();   // drains vmcnt -> all sc1 stores acked at coherence point
    if (tid == 0)
      ast(p.flags + (size_t)bid * 16, (unsigned)(j + 1));

    // issue next-step emb loads NOW; they fly during the gen-wait
    if (j + 1 < SEQ) {
      if (use_pk) {
        const uint4* src = (const uint4*)(p.embP + (size_t)tk_pk * NH);
#pragma unroll
        for (int q = 0; q < 16; ++q) epr.u[q] = src[lp + q * 8];
      } else if (do_epf) {
        const float* e = p.emb + (size_t)tk_st * NH + ks;
#pragma unroll
        for (int q = 0; q < 16; ++q) epr.f[q] = *(const float4*)(e + q * 4);
      }
    }

    if (bid == 0) {
      unsigned* f = p.flags + (size_t)tid * 16;
      while (ald(f) < (unsigned)(j + 1)) __builtin_amdgcn_s_sleep(1);
      __syncthreads();
      if (tid == 0) ast(p.gen, (unsigned)(j + 1));
    } else {
      if (tid < 64) {
        while (ald(p.gen) < (unsigned)(j + 1)) __builtin_amdgcn_s_sleep(1);
      }
      __syncthreads();
    }
  }

  // ---- epilogue: backward final carries bh1,bc1,bh2,bc2 ----
  if (dl == 2) {
    p.out[(size_t)SEQ * BH + 0 * (size_t)BH + (size_t)(b0 + cb) * NH + uG] = h_reg;
    p.out[(size_t)SEQ * BH + 1 * (size_t)BH + (size_t)(b0 + cb) * NH + uG] = c_reg;
  } else if (dl == 3) {
    p.out[(size_t)SEQ * BH + 2 * (size_t)BH + (size_t)(b0 + cb) * NH + uG] = h_reg;
    p.out[(size_t)SEQ * BH + 3 * (size_t)BH + (size_t)(b0 + cb) * NH + uG] = c_reg;
  }
}

extern "C" void kernel_launch(void* const* d_in, const int* in_sizes, int n_in,
                              void* d_out, int out_size, void* d_ws, size_t ws_size,
                              hipStream_t stream) {
  P p;
  p.word = (const int*)d_in[0];
  p.emb  = (const float*)d_in[1];
  for (int i = 0; i < 4; ++i) {
    p.Wih[i] = (const float*)d_in[2 + i * 4 + 0];
    p.Whh[i] = (const float*)d_in[2 + i * 4 + 1];
    p.bih[i] = (const float*)d_in[2 + i * 4 + 2];
    p.bhh[i] = (const float*)d_in[2 + i * 4 + 3];
  }
  unsigned char* ws = (unsigned char*)d_ws;
  p.flags = (unsigned*)ws;                       // 16 KB (256 x 64B slots)
  p.gen   = (unsigned*)(ws + 16384);             // one 64B line
  p.hpk   = (unsigned*)(ws + 16448);             // 512 KB packed h
  const size_t embOff  = (size_t)1 << 20;        // 1 MB
  const size_t embBytes = (size_t)NV * NH * 4;   // 62.5 MB packed table
  if (ws_size >= embOff + embBytes) {
    p.embP = (const unsigned*)(ws + embOff);
  } else {
    p.embP = nullptr;
  }
  p.out = (float*)d_out;

  hipMemsetAsync(d_ws, 0, 16448 + (size_t)8 * BH * 4, stream);

  if (p.embP) {
    // NV*NH = 16,384,000 elems, 8/thread -> 8000 blocks x 256
    hipLaunchKernelGGL(conv_embp, dim3(8000), dim3(256), 0, stream,
                       p.emb, (unsigned*)p.embP);
  }

  // used: 32*KP*2 + 4*4*16*20*4 = 86528 B; request 88 KB to keep 1 block/CU
  const int smem = 90112;
  hipFuncSetAttribute(reinterpret_cast<const void*>(enc_persist),
                      hipFuncAttributeMaxDynamicSharedMemorySize, smem);
  hipLaunchKernelGGL(enc_persist, dim3(256), dim3(256), smem, stream, p);
}